// Round 16
// baseline (106.163 us; speedup 1.0000x reference)
//
#include <hip/hip_runtime.h>

// Problem constants (B=4, N=2048, DIM=1024, HEAD=16, HD=64)
#define B_    4
#define N_    2048
#define DIM_  1024
#define HEAD_ 16
#define HD_   64
#define M_    (B_*N_)    // 8192 rows
#define E_    (2*DIM_)   // 2048 projection outputs

typedef short          frag8 __attribute__((ext_vector_type(8)));  // 8 bf16 (4 VGPRs)
typedef float          facc4 __attribute__((ext_vector_type(4)));  // MFMA accum
typedef unsigned short ush4  __attribute__((ext_vector_type(4)));
typedef _Float16       hv4   __attribute__((ext_vector_type(4)));  // 4 f16 (2 VGPRs)
typedef _Float16       hv2   __attribute__((ext_vector_type(2)));

#define AS1 __attribute__((address_space(1)))
#define AS3 __attribute__((address_space(3)))

__device__ __forceinline__ void gld_lds16(const void* g, void* l) {
    // async global->LDS, 16B per lane; LDS dest = wave-uniform base + lane*16
    __builtin_amdgcn_global_load_lds((AS1 void*)(void*)g, (AS3 void*)l, 16, 0, 0);
}

__device__ __forceinline__ unsigned short f2bf(float f) {
    return __builtin_bit_cast(unsigned short, (__bf16)f);
}

// ---------------- Kernel 1: fused prep (LN -> bf16 | Wqk cvt | vprep f16) ---
__global__ __launch_bounds__(256) void prep_kernel(const float* __restrict__ x,
                                                   const float* __restrict__ lw,
                                                   const float* __restrict__ lb,
                                                   const float* __restrict__ Wqk,
                                                   const float* __restrict__ A,
                                                   const float* __restrict__ wv,
                                                   unsigned short* __restrict__ xn,
                                                   unsigned short* __restrict__ wb,
                                                   unsigned short* __restrict__ v16) {
    __shared__ float red[8];
    const int bid = blockIdx.x;
    const int t   = threadIdx.x;
    if (bid < M_) {
        // LayerNorm row
        const float4 v = ((const float4*)(x + (size_t)bid * DIM_))[t];
        float s  = v.x + v.y + v.z + v.w;
        float sq = v.x*v.x + v.y*v.y + v.z*v.z + v.w*v.w;
#pragma unroll
        for (int off = 32; off > 0; off >>= 1) {
            s  += __shfl_xor(s,  off);
            sq += __shfl_xor(sq, off);
        }
        const int w = t >> 6;
        if ((t & 63) == 0) { red[w] = s; red[4 + w] = sq; }
        __syncthreads();
        s  = red[0] + red[1] + red[2] + red[3];
        sq = red[4] + red[5] + red[6] + red[7];
        const float mu   = s * (1.0f / DIM_);
        const float rstd = rsqrtf(sq * (1.0f / DIM_) - mu * mu + 1e-5f);
        const float4 wv4 = ((const float4*)lw)[t];
        const float4 bv4 = ((const float4*)lb)[t];
        ush4 o;
        o[0] = f2bf((v.x - mu) * rstd * wv4.x + bv4.x);
        o[1] = f2bf((v.y - mu) * rstd * wv4.y + bv4.y);
        o[2] = f2bf((v.z - mu) * rstd * wv4.z + bv4.z);
        o[3] = f2bf((v.w - mu) * rstd * wv4.w + bv4.w);
        *(ush4*)(xn + (size_t)bid * DIM_ + t * 4) = o;
    } else if (bid < M_ + 2048) {
        // Wqk f32 -> bf16 (524288 float4 groups)
        const int i = (bid - M_) * 256 + t;
        const float4 v = ((const float4*)Wqk)[i];
        ush4 o;
        o[0] = f2bf(v.x); o[1] = f2bf(v.y); o[2] = f2bf(v.z); o[3] = f2bf(v.w);
        ((ush4*)wb)[i] = o;
    } else {
        // v16[bh][n] = (f16)(A[b][n][h] * wv)
        const int bh = bid - (M_ + 2048);
        const int b = bh >> 4, h = bh & 15;
        const float wvv = wv[0];
#pragma unroll
        for (int i = 0; i < 8; ++i) {
            const int n = i * 256 + t;
            const float f = A[((size_t)(b * N_ + n)) * HEAD_ + h] * wvv;
            v16[(size_t)bh * N_ + n] = __builtin_bit_cast(unsigned short, (_Float16)f);
        }
    }
}

// ---------------- Kernel 2: qk = xn @ Wqk^T  (256x256 deep-pipelined) -------
// (unchanged from r14/r15 — verified out of top-5)
__global__ __launch_bounds__(512, 2) void gemm_qk(const unsigned short* __restrict__ xn,
                                                  const unsigned short* __restrict__ wb,
                                                  unsigned short* __restrict__ qo,
                                                  unsigned short* __restrict__ ko) {
    __shared__ __attribute__((aligned(16))) char lds[131072];
    const int t    = threadIdx.x;             // 0..511
    const int lane = t & 63;
    const int wid  = t >> 6;                  // 0..7
    const int wr   = wid >> 2, wc = wid & 3;  // 2x4 wave grid, 128x64 each
    const int lr   = lane & 15, lg = lane >> 4;
    const int bid  = blockIdx.x;
    const int xcd  = bid & 7;                 // dispatch round-robins XCDs
    const int l    = bid >> 3;                // 0..31 within XCD
    const int bm   = (xcd << 2) | (l & 3);    // 4-panel bm slice per XCD
    const int bn   = l >> 2;                  // 0..7
    const int m0   = bm * 256, e0 = bn * 256;

    const int srow = t >> 3;                  // 0..63
    const int ss8  = ((t & 7) ^ (srow & 7)) * 8;
    const int wu16 = (t & ~63) * 16;

    facc4 acc[8][4] = {};
    frag8 a[4][2], b[2][2];

#define STG(mat, tile, half) do {                                              \
        const unsigned short* sp_ = (mat) ? wb : xn;                           \
        const int rb_ = (mat) ? e0 : m0;                                       \
        _Pragma("unroll")                                                      \
        for (int l_ = 0; l_ < 2; ++l_)                                         \
            gld_lds16(sp_ + (size_t)(rb_ + (half)*128 + l_*64 + srow) * DIM_   \
                          + (tile)*64 + ss8,                                   \
                      lds + ((tile)&1)*65536 + (mat)*32768 + (half)*16384      \
                          + l_*8192 + wu16);                                   \
    } while (0)

#define LDA(mh) do {                                                           \
        _Pragma("unroll")                                                      \
        for (int mf_ = 0; mf_ < 4; ++mf_) {                                    \
            const int row_ = wr*128 + (mh)*64 + mf_*16 + lr;                   \
            const int sw_  = (row_ & 7) << 4;                                  \
            const char* ab_ = lds + cb*65536;                                  \
            a[mf_][0] = *(const frag8*)(ab_ + row_*128 + ((lg*16) ^ sw_));     \
            a[mf_][1] = *(const frag8*)(ab_ + row_*128 + ((64 + lg*16) ^ sw_));\
        }                                                                      \
    } while (0)

#define LDB(nh) do {                                                           \
        _Pragma("unroll")                                                      \
        for (int nf_ = 0; nf_ < 2; ++nf_) {                                    \
            const int row_ = wc*64 + (nh)*32 + nf_*16 + lr;                    \
            const int sw_  = (row_ & 7) << 4;                                  \
            const char* bb_ = lds + cb*65536 + 32768;                          \
            b[nf_][0] = *(const frag8*)(bb_ + row_*128 + ((lg*16) ^ sw_));     \
            b[nf_][1] = *(const frag8*)(bb_ + row_*128 + ((64 + lg*16) ^ sw_));\
        }                                                                      \
    } while (0)

#define MM(mh, nh) do {                                                        \
        __builtin_amdgcn_s_setprio(1);                                         \
        _Pragma("unroll")                                                      \
        for (int mf_ = 0; mf_ < 4; ++mf_)                                      \
        _Pragma("unroll")                                                      \
        for (int nf_ = 0; nf_ < 2; ++nf_) {                                    \
            acc[(mh)*4+mf_][(nh)*2+nf_] = __builtin_amdgcn_mfma_f32_16x16x32_bf16( \
                a[mf_][0], b[nf_][0], acc[(mh)*4+mf_][(nh)*2+nf_], 0, 0, 0);   \
            acc[(mh)*4+mf_][(nh)*2+nf_] = __builtin_amdgcn_mfma_f32_16x16x32_bf16( \
                a[mf_][1], b[nf_][1], acc[(mh)*4+mf_][(nh)*2+nf_], 0, 0, 0);   \
        }                                                                      \
        __builtin_amdgcn_s_setprio(0);                                         \
    } while (0)

#define PH_SYNC(NW) do {                                                       \
        asm volatile("s_waitcnt vmcnt(" NW ")" ::: "memory");                  \
        __builtin_amdgcn_s_barrier();                                          \
        asm volatile("" ::: "memory");                                         \
    } while (0)
#define PH_BAR() do {                                                          \
        __builtin_amdgcn_s_barrier();                                          \
        asm volatile("" ::: "memory");                                         \
    } while (0)
#define PH_LGKM() do {                                                         \
        asm volatile("s_waitcnt lgkmcnt(0)" ::: "memory");                     \
        __builtin_amdgcn_sched_barrier(0);                                     \
    } while (0)

    STG(0, 0, 0);  STG(1, 0, 0);  STG(0, 0, 1);  STG(1, 0, 1);
    STG(0, 1, 0);  STG(0, 1, 1);  STG(1, 1, 0);

    for (int m = 0; m < 15; ++m) {
        const int cb = m & 1;
        PH_SYNC("8");
        LDA(0); LDB(0);
        STG(1, m + 1, 1);
        PH_LGKM();
        MM(0, 0);
        PH_SYNC("8");
        LDB(1);
        if (m <= 13) STG(0, m + 2, 0);
        PH_LGKM();
        MM(0, 1);
        PH_SYNC("8");
        LDA(1); LDB(0);
        PH_LGKM();
        MM(1, 0);
        PH_SYNC("8");
        LDB(1);
        if (m <= 13) { STG(0, m + 2, 1); STG(1, m + 2, 0); }
        PH_LGKM();
        MM(1, 1);
    }
    {
        const int cb = 1;
        PH_SYNC("2");  LDA(0); LDB(0); PH_LGKM(); MM(0, 0);
        PH_SYNC("0");  LDB(1);         PH_LGKM(); MM(0, 1);
        PH_BAR();      LDA(1); LDB(0); PH_LGKM(); MM(1, 0);
        PH_BAR();      LDB(1);         PH_LGKM(); MM(1, 1);
    }
#undef STG
#undef LDA
#undef LDB
#undef MM
#undef PH_SYNC
#undef PH_BAR
#undef PH_LGKM

    const float QSCALE = 0.03125f * 1.4426950408889634f;
#pragma unroll
    for (int mf8 = 0; mf8 < 8; ++mf8) {
#pragma unroll
        for (int nf4 = 0; nf4 < 4; ++nf4) {
            const int eg = e0 + wc * 64 + nf4 * 16 + lr;
#pragma unroll
            for (int r = 0; r < 4; ++r) {
                const int   mg = m0 + wr * 128 + mf8 * 16 + lg * 4 + r;
                const int   b_  = mg >> 11;
                const int   n  = mg & (N_ - 1);
                const float val = acc[mf8][nf4][r];
                if (eg < DIM_) {
                    const int h = eg >> 6, d = eg & 63;
                    qo[((size_t)((b_ * HEAD_ + h) * N_ + n)) * HD_ + d] = f2bf(val * QSCALE);
                } else {
                    const int e2 = eg - DIM_;
                    const int h = e2 >> 6, d = e2 & 63;
                    ko[((size_t)((b_ * HEAD_ + h) * N_ + n)) * HD_ + d] = f2bf(val);
                }
            }
        }
    }
}

// ---------------- Kernel 3: attention partials (zero-barrier, wave-private) -
// Hypothesis under test: the 54-56 us plateau (6 variants) is block-barrier
// lockstep, not pipe demand. Each wave now owns a PRIVATE 4-buffer LDS ring
// (4 x 2KB = 8KB/wave) holding 16-row K chunks, ordered only by that wave's
// own vmcnt (per-wave counter) — NO s_barrier anywhere. The 4 waves of a
// block read the same global K lines (L1 serves repeats). 3-deep prefetch,
// gate vmcnt(4). sched_barrier(0) per iter pins the previous chunk's
// lgkm-waits/MFMAs before the buffer-overwriting stage (WAR safety).
// Grid: XCD-locality mapping — bid&7 = XCD owns bh in [xcd*8,xcd*8+8) for
// all splits/qblks: K+Q working set ~4MB = L2, so sibling re-reads hit L2.
__global__ __launch_bounds__(256) void attn_kernel(const unsigned short* __restrict__ q,
                                                   const unsigned short* __restrict__ kmat,
                                                   const unsigned short* __restrict__ v16,
                                                   float2* __restrict__ part) {
    __shared__ __attribute__((aligned(16))) char KsB[4 * 8192];   // 8KB per wave
    const int t    = threadIdx.x;
    const int lane = t & 63, w = t >> 6;        // 4 waves, 64 q-rows each
    const int lr   = lane & 15, lg = lane >> 4;
    const int bid   = blockIdx.x;               // 0..2047
    const int xcd   = bid & 7;
    const int inner = (bid >> 3) & 31;
    const int qblk  = bid >> 8;                 // 0..7
    const int s     = xcd * 32 + inner;         // 0..255
    const int bh    = s >> 2, split = s & 3;
    const int b     = bh >> 4, h = bh & 15;
    const int q0    = qblk * 256 + w * 64;

    // per-lane staging offsets (8 rows per gld issue, both-sides swizzle)
    const int koff  = (lane >> 3) * HD_ + (((lane & 7) ^ ((lane >> 3) & 7)) * 8);
    const int sw    = (lr & 7) << 4;
    const int off_h0 = lr * 128 + ((lg * 16) ^ sw);
    const int off_h1 = lr * 128 + ((64 + lg * 16) ^ sw);
    char* myl = KsB + w * 8192;                 // wave-private LDS ring

    const unsigned short* qbase = q    + (size_t)bh * N_ * HD_;
    const unsigned short* kfix  = kmat + (size_t)bh * N_ * HD_ + (size_t)split * 512 * HD_;
    const unsigned short* vc    = v16  + (size_t)bh * N_ + split * 512;

    frag8 qf[4][2];
#pragma unroll
    for (int qt = 0; qt < 4; ++qt) {
#pragma unroll
        for (int hh = 0; hh < 2; ++hh)
            qf[qt][hh] = *(const frag8*)(qbase + (size_t)(q0 + qt * 16 + lr) * HD_ + hh * 32 + lg * 8);
    }

    hv4 sel, one1;
#pragma unroll
    for (int j = 0; j < 4; ++j) {
        sel[j]  = (lr == 0) ? (_Float16)1.f : (_Float16)0.f;
        one1[j] = (lr == 1) ? (_Float16)1.f : (_Float16)0.f;
    }
    const facc4 z4 = {0.f, 0.f, 0.f, 0.f};
    facc4 acc[4] = {};

#define STAGE(BUF, P) do {                                                     \
        gld_lds16((P) + koff,       myl + (BUF) * 2048);                       \
        gld_lds16((P) + 512 + koff, myl + (BUF) * 2048 + 1024);                \
    } while (0)

#define CHUNK(J) do {                                                          \
        const frag8 kf0 = *(const frag8*)(myl + (J) * 2048 + off_h0);          \
        const frag8 kf1 = *(const frag8*)(myl + (J) * 2048 + off_h1);          \
        const hv4 vv = *(const hv4*)(vc + lg * 4);                             \
        const hv4 av = vv * sel + one1;                                        \
        __builtin_amdgcn_s_setprio(1);                                         \
        _Pragma("unroll")                                                      \
        for (int qt = 0; qt < 4; ++qt) {                                       \
            facc4 s_ = __builtin_amdgcn_mfma_f32_16x16x32_bf16(kf0, qf[qt][0], z4, 0, 0, 0); \
            s_ = __builtin_amdgcn_mfma_f32_16x16x32_bf16(kf1, qf[qt][1], s_, 0, 0, 0); \
            const hv2 p01 = __builtin_bit_cast(hv2,                            \
                __builtin_amdgcn_cvt_pkrtz(__builtin_amdgcn_exp2f(s_[0]),      \
                                           __builtin_amdgcn_exp2f(s_[1])));    \
            const hv2 p23 = __builtin_bit_cast(hv2,                            \
                __builtin_amdgcn_cvt_pkrtz(__builtin_amdgcn_exp2f(s_[2]),      \
                                           __builtin_amdgcn_exp2f(s_[3])));    \
            hv4 pb; pb[0] = p01[0]; pb[1] = p01[1]; pb[2] = p23[0]; pb[3] = p23[1]; \
            acc[qt] = __builtin_amdgcn_mfma_f32_16x16x16f16(av, pb, acc[qt], 0, 0, 0); \
        }                                                                      \
        __builtin_amdgcn_s_setprio(0);                                         \
        vc += 16;                                                              \
    } while (0)

// per-wave gate: own vmcnt only (no barrier). sched_barrier pins the prior
// chunk's lgkm-waits/MFMAs before this iter's buffer-overwriting STAGE.
#define VM(NW) {                                                               \
        asm volatile("s_waitcnt vmcnt(" NW ")" ::: "memory");                  \
        __builtin_amdgcn_sched_barrier(0);                                     \
    }

    STAGE(0, kfix);
    STAGE(1, kfix + 1024);
    STAGE(2, kfix + 2048);
    const unsigned short* kst = kfix + 3 * 1024;

    for (int o = 0; o < 7; ++o) {
        VM("4") STAGE(3, kst); kst += 1024; CHUNK(0);
        VM("4") STAGE(0, kst); kst += 1024; CHUNK(1);
        VM("4") STAGE(1, kst); kst += 1024; CHUNK(2);
        VM("4") STAGE(2, kst); kst += 1024; CHUNK(3);
    }
    VM("4") STAGE(3, kst); CHUNK(0);   // c=28, stages chunk 31
    VM("4") CHUNK(1);                  // c=29
    VM("2") CHUNK(2);                  // c=30
    VM("0") CHUNK(3);                  // c=31

#undef STAGE
#undef CHUNK
#undef VM

    if (lg == 0) {
#pragma unroll
        for (int qt = 0; qt < 4; ++qt) {
            const int row = q0 + qt * 16 + lr;
            float2 pr; pr.x = acc[qt][0]; pr.y = acc[qt][1];
            part[(size_t)split * (M_ * HEAD_) + ((size_t)(b * N_ + row)) * HEAD_ + h] = pr;
        }
    }
}

// ---------------- Kernel 4: combine split-KV partials --------------------
__global__ __launch_bounds__(256) void reduce_kernel(const float2* __restrict__ part,
                                                     const float* __restrict__ Ain,
                                                     float* __restrict__ outp) {
    const int i = blockIdx.x * 256 + threadIdx.x;   // 0..131071 == out layout
    const float2 p0 = part[i];
    const float2 p1 = part[1 * (M_ * HEAD_) + i];
    const float2 p2 = part[2 * (M_ * HEAD_) + i];
    const float2 p3 = part[3 * (M_ * HEAD_) + i];
    outp[i] = Ain[i] + (p0.x + p1.x + p2.x + p3.x) / (p0.y + p1.y + p2.y + p3.y);
}

// ---------------- launch ----------------
extern "C" void kernel_launch(void* const* d_in, const int* in_sizes, int n_in,
                              void* d_out, int out_size, void* d_ws, size_t ws_size,
                              hipStream_t stream) {
    const float* x   = (const float*)d_in[0];
    const float* A   = (const float*)d_in[1];
    const float* lw  = (const float*)d_in[2];
    const float* lb  = (const float*)d_in[3];
    const float* Wqk = (const float*)d_in[4];
    const float* wv  = (const float*)d_in[5];
    float* outp = (float*)d_out;

    char* ws = (char*)d_ws;
    unsigned short* xn  = (unsigned short*)(ws);                      // 16 MB (dead after gemm)
    unsigned short* wb  = (unsigned short*)(ws + 16u * 1024 * 1024);  //  4 MB
    unsigned short* qb  = (unsigned short*)(ws + 20u * 1024 * 1024);  // 16 MB
    unsigned short* kb  = (unsigned short*)(ws + 36u * 1024 * 1024);  // 16 MB
    unsigned short* v16 = (unsigned short*)(ws + 52u * 1024 * 1024);  // 256 KB
    float2*         part = (float2*)(ws);                             // 4 MB, reuses xn region

    prep_kernel<<<M_ + 2048 + B_ * HEAD_, 256, 0, stream>>>(x, lw, lb, Wqk, A, wv, xn, wb, v16);
    gemm_qk<<<256, 512, 0, stream>>>(xn, wb, qb, kb);
    attn_kernel<<<2048, 256, 0, stream>>>(qb, kb, v16, part);
    reduce_kernel<<<(M_ * HEAD_) / 256, 256, 0, stream>>>(part, A, outp);
}

// Round 17
// 94.268 us; speedup vs baseline: 1.1262x; 1.1262x over previous
//
#include <hip/hip_runtime.h>

// Problem constants (B=4, N=2048, DIM=1024, HEAD=16, HD=64)
#define B_    4
#define N_    2048
#define DIM_  1024
#define HEAD_ 16
#define HD_   64
#define M_    (B_*N_)    // 8192 rows
#define E_    (2*DIM_)   // 2048 projection outputs

typedef short          frag8 __attribute__((ext_vector_type(8)));  // 8 bf16 (4 VGPRs)
typedef float          facc4 __attribute__((ext_vector_type(4)));  // MFMA accum
typedef unsigned short ush4  __attribute__((ext_vector_type(4)));
typedef _Float16       hv4   __attribute__((ext_vector_type(4)));  // 4 f16 (2 VGPRs)
typedef _Float16       hv2   __attribute__((ext_vector_type(2)));

#define AS1 __attribute__((address_space(1)))
#define AS3 __attribute__((address_space(3)))

__device__ __forceinline__ void gld_lds16(const void* g, void* l) {
    // async global->LDS, 16B per lane; LDS dest = wave-uniform base + lane*16
    __builtin_amdgcn_global_load_lds((AS1 void*)(void*)g, (AS3 void*)l, 16, 0, 0);
}

__device__ __forceinline__ unsigned short f2bf(float f) {
    return __builtin_bit_cast(unsigned short, (__bf16)f);
}

// ---------------- Kernel 1: fused prep (LN -> bf16 | Wqk cvt | vprep f16) ---
__global__ __launch_bounds__(256) void prep_kernel(const float* __restrict__ x,
                                                   const float* __restrict__ lw,
                                                   const float* __restrict__ lb,
                                                   const float* __restrict__ Wqk,
                                                   const float* __restrict__ A,
                                                   const float* __restrict__ wv,
                                                   unsigned short* __restrict__ xn,
                                                   unsigned short* __restrict__ wb,
                                                   unsigned short* __restrict__ v16) {
    __shared__ float red[8];
    const int bid = blockIdx.x;
    const int t   = threadIdx.x;
    if (bid < M_) {
        // LayerNorm row
        const float4 v = ((const float4*)(x + (size_t)bid * DIM_))[t];
        float s  = v.x + v.y + v.z + v.w;
        float sq = v.x*v.x + v.y*v.y + v.z*v.z + v.w*v.w;
#pragma unroll
        for (int off = 32; off > 0; off >>= 1) {
            s  += __shfl_xor(s,  off);
            sq += __shfl_xor(sq, off);
        }
        const int w = t >> 6;
        if ((t & 63) == 0) { red[w] = s; red[4 + w] = sq; }
        __syncthreads();
        s  = red[0] + red[1] + red[2] + red[3];
        sq = red[4] + red[5] + red[6] + red[7];
        const float mu   = s * (1.0f / DIM_);
        const float rstd = rsqrtf(sq * (1.0f / DIM_) - mu * mu + 1e-5f);
        const float4 wv4 = ((const float4*)lw)[t];
        const float4 bv4 = ((const float4*)lb)[t];
        ush4 o;
        o[0] = f2bf((v.x - mu) * rstd * wv4.x + bv4.x);
        o[1] = f2bf((v.y - mu) * rstd * wv4.y + bv4.y);
        o[2] = f2bf((v.z - mu) * rstd * wv4.z + bv4.z);
        o[3] = f2bf((v.w - mu) * rstd * wv4.w + bv4.w);
        *(ush4*)(xn + (size_t)bid * DIM_ + t * 4) = o;
    } else if (bid < M_ + 2048) {
        // Wqk f32 -> bf16 (524288 float4 groups)
        const int i = (bid - M_) * 256 + t;
        const float4 v = ((const float4*)Wqk)[i];
        ush4 o;
        o[0] = f2bf(v.x); o[1] = f2bf(v.y); o[2] = f2bf(v.z); o[3] = f2bf(v.w);
        ((ush4*)wb)[i] = o;
    } else {
        // v16[bh][n] = (f16)(A[b][n][h] * wv)
        const int bh = bid - (M_ + 2048);
        const int b = bh >> 4, h = bh & 15;
        const float wvv = wv[0];
#pragma unroll
        for (int i = 0; i < 8; ++i) {
            const int n = i * 256 + t;
            const float f = A[((size_t)(b * N_ + n)) * HEAD_ + h] * wvv;
            v16[(size_t)bh * N_ + n] = __builtin_bit_cast(unsigned short, (_Float16)f);
        }
    }
}

// ---------------- Kernel 2: qk = xn @ Wqk^T  (256x256 deep-pipelined) -------
// (unchanged from r14/r15 — verified out of top-5)
__global__ __launch_bounds__(512, 2) void gemm_qk(const unsigned short* __restrict__ xn,
                                                  const unsigned short* __restrict__ wb,
                                                  unsigned short* __restrict__ qo,
                                                  unsigned short* __restrict__ ko) {
    __shared__ __attribute__((aligned(16))) char lds[131072];
    const int t    = threadIdx.x;             // 0..511
    const int lane = t & 63;
    const int wid  = t >> 6;                  // 0..7
    const int wr   = wid >> 2, wc = wid & 3;  // 2x4 wave grid, 128x64 each
    const int lr   = lane & 15, lg = lane >> 4;
    const int bid  = blockIdx.x;
    const int xcd  = bid & 7;                 // dispatch round-robins XCDs
    const int l    = bid >> 3;                // 0..31 within XCD
    const int bm   = (xcd << 2) | (l & 3);    // 4-panel bm slice per XCD
    const int bn   = l >> 2;                  // 0..7
    const int m0   = bm * 256, e0 = bn * 256;

    const int srow = t >> 3;                  // 0..63
    const int ss8  = ((t & 7) ^ (srow & 7)) * 8;
    const int wu16 = (t & ~63) * 16;

    facc4 acc[8][4] = {};
    frag8 a[4][2], b[2][2];

#define STG(mat, tile, half) do {                                              \
        const unsigned short* sp_ = (mat) ? wb : xn;                           \
        const int rb_ = (mat) ? e0 : m0;                                       \
        _Pragma("unroll")                                                      \
        for (int l_ = 0; l_ < 2; ++l_)                                         \
            gld_lds16(sp_ + (size_t)(rb_ + (half)*128 + l_*64 + srow) * DIM_   \
                          + (tile)*64 + ss8,                                   \
                      lds + ((tile)&1)*65536 + (mat)*32768 + (half)*16384      \
                          + l_*8192 + wu16);                                   \
    } while (0)

#define LDA(mh) do {                                                           \
        _Pragma("unroll")                                                      \
        for (int mf_ = 0; mf_ < 4; ++mf_) {                                    \
            const int row_ = wr*128 + (mh)*64 + mf_*16 + lr;                   \
            const int sw_  = (row_ & 7) << 4;                                  \
            const char* ab_ = lds + cb*65536;                                  \
            a[mf_][0] = *(const frag8*)(ab_ + row_*128 + ((lg*16) ^ sw_));     \
            a[mf_][1] = *(const frag8*)(ab_ + row_*128 + ((64 + lg*16) ^ sw_));\
        }                                                                      \
    } while (0)

#define LDB(nh) do {                                                           \
        _Pragma("unroll")                                                      \
        for (int nf_ = 0; nf_ < 2; ++nf_) {                                    \
            const int row_ = wc*64 + (nh)*32 + nf_*16 + lr;                    \
            const int sw_  = (row_ & 7) << 4;                                  \
            const char* bb_ = lds + cb*65536 + 32768;                          \
            b[nf_][0] = *(const frag8*)(bb_ + row_*128 + ((lg*16) ^ sw_));     \
            b[nf_][1] = *(const frag8*)(bb_ + row_*128 + ((64 + lg*16) ^ sw_));\
        }                                                                      \
    } while (0)

#define MM(mh, nh) do {                                                        \
        __builtin_amdgcn_s_setprio(1);                                         \
        _Pragma("unroll")                                                      \
        for (int mf_ = 0; mf_ < 4; ++mf_)                                      \
        _Pragma("unroll")                                                      \
        for (int nf_ = 0; nf_ < 2; ++nf_) {                                    \
            acc[(mh)*4+mf_][(nh)*2+nf_] = __builtin_amdgcn_mfma_f32_16x16x32_bf16( \
                a[mf_][0], b[nf_][0], acc[(mh)*4+mf_][(nh)*2+nf_], 0, 0, 0);   \
            acc[(mh)*4+mf_][(nh)*2+nf_] = __builtin_amdgcn_mfma_f32_16x16x32_bf16( \
                a[mf_][1], b[nf_][1], acc[(mh)*4+mf_][(nh)*2+nf_], 0, 0, 0);   \
        }                                                                      \
        __builtin_amdgcn_s_setprio(0);                                         \
    } while (0)

#define PH_SYNC(NW) do {                                                       \
        asm volatile("s_waitcnt vmcnt(" NW ")" ::: "memory");                  \
        __builtin_amdgcn_s_barrier();                                          \
        asm volatile("" ::: "memory");                                         \
    } while (0)
#define PH_BAR() do {                                                          \
        __builtin_amdgcn_s_barrier();                                          \
        asm volatile("" ::: "memory");                                         \
    } while (0)
#define PH_LGKM() do {                                                         \
        asm volatile("s_waitcnt lgkmcnt(0)" ::: "memory");                     \
        __builtin_amdgcn_sched_barrier(0);                                     \
    } while (0)

    STG(0, 0, 0);  STG(1, 0, 0);  STG(0, 0, 1);  STG(1, 0, 1);
    STG(0, 1, 0);  STG(0, 1, 1);  STG(1, 1, 0);

    for (int m = 0; m < 15; ++m) {
        const int cb = m & 1;
        PH_SYNC("8");
        LDA(0); LDB(0);
        STG(1, m + 1, 1);
        PH_LGKM();
        MM(0, 0);
        PH_SYNC("8");
        LDB(1);
        if (m <= 13) STG(0, m + 2, 0);
        PH_LGKM();
        MM(0, 1);
        PH_SYNC("8");
        LDA(1); LDB(0);
        PH_LGKM();
        MM(1, 0);
        PH_SYNC("8");
        LDB(1);
        if (m <= 13) { STG(0, m + 2, 1); STG(1, m + 2, 0); }
        PH_LGKM();
        MM(1, 1);
    }
    {
        const int cb = 1;
        PH_SYNC("2");  LDA(0); LDB(0); PH_LGKM(); MM(0, 0);
        PH_SYNC("0");  LDB(1);         PH_LGKM(); MM(0, 1);
        PH_BAR();      LDA(1); LDB(0); PH_LGKM(); MM(1, 0);
        PH_BAR();      LDB(1);         PH_LGKM(); MM(1, 1);
    }
#undef STG
#undef LDA
#undef LDB
#undef MM
#undef PH_SYNC
#undef PH_BAR
#undef PH_LGKM

    const float QSCALE = 0.03125f * 1.4426950408889634f;
#pragma unroll
    for (int mf8 = 0; mf8 < 8; ++mf8) {
#pragma unroll
        for (int nf4 = 0; nf4 < 4; ++nf4) {
            const int eg = e0 + wc * 64 + nf4 * 16 + lr;
#pragma unroll
            for (int r = 0; r < 4; ++r) {
                const int   mg = m0 + wr * 128 + mf8 * 16 + lg * 4 + r;
                const int   b_  = mg >> 11;
                const int   n  = mg & (N_ - 1);
                const float val = acc[mf8][nf4][r];
                if (eg < DIM_) {
                    const int h = eg >> 6, d = eg & 63;
                    qo[((size_t)((b_ * HEAD_ + h) * N_ + n)) * HD_ + d] = f2bf(val * QSCALE);
                } else {
                    const int e2 = eg - DIM_;
                    const int h = e2 >> 6, d = e2 & 63;
                    ko[((size_t)((b_ * HEAD_ + h) * N_ + n)) * HD_ + d] = f2bf(val);
                }
            }
        }
    }
}

// ---------------- Kernel 3: attention partials (r15 8-wave + vmcnt-clean) ---
// FIX under test (explains the 7-variant 54-61 us plateau): the per-chunk vv
// GLOBAL loads polluted vmcnt — vmcnt retires in issue order, and the vv
// loads issued inside CHUNK(c) are younger than STAGE(c+2), so the next
// iter's vmcnt(1) gate actually drained ALL staging + 3 L2-latency vv loads
// every chunk (counted pipeline was de-facto vmcnt(0) since r7). Now the v16
// slice (1 KB) is staged into LDS ONCE in the prologue and vv comes from a
// broadcast ds_read -> the loop's only VMEM ops are the staging gld_lds16,
// so the gates keep 2 chunks genuinely in flight. Also: r16's proven
// XCD-locality grid remap (FETCH 63->17 MB).
__global__ __launch_bounds__(512) void attn_kernel(const unsigned short* __restrict__ q,
                                                   const unsigned short* __restrict__ kmat,
                                                   const unsigned short* __restrict__ v16,
                                                   float2* __restrict__ part) {
    __shared__ __attribute__((aligned(16))) char KsB[3 * 8192];
    __shared__ __attribute__((aligned(8)))  unsigned short Vs[512];
    const int t    = threadIdx.x;               // 0..511
    const int lane = t & 63, w = t >> 6;        // 8 waves, 64 q-rows each
    const int lr   = lane & 15, lg = lane >> 4;
    const int bid  = blockIdx.x;                // 0..1023
    // XCD-locality: xcd owns 8 bh (2MB K + 2MB Q ~ L2) x all splits/qblks
    const int xcd   = bid & 7;
    const int r_    = bid >> 3;                 // 0..127
    const int bh    = xcd * 8 + (r_ & 7);
    const int split = (r_ >> 3) & 3;
    const int qblk  = r_ >> 5;                  // 0..3
    const int b     = bh >> 4, h = bh & 15;
    const int q0    = qblk * 512 + w * 64;

    const int row0  = t >> 3;                   // 0..63
    const int koff  = row0 * HD_ + (((t & 7) ^ (row0 & 7)) * 8);
    const int wbase = (t & ~63) * 16;           // per-wave 1KB LDS slice
    const int sw    = (lr & 7) << 4;
    const int off_h0 = lr * 128 + ((lg * 16) ^ sw);
    const int off_h1 = lr * 128 + ((64 + lg * 16) ^ sw);

    const unsigned short* qbase = q    + (size_t)bh * N_ * HD_;
    const unsigned short* kfix  = kmat + (size_t)bh * N_ * HD_ + (size_t)split * 512 * HD_;
    const unsigned short* vfix  = v16  + (size_t)bh * N_ + split * 512;

    // v slice -> LDS once (removes vv from the loop's VMEM counter path)
    Vs[t] = vfix[t];

    frag8 qf[4][2];
#pragma unroll
    for (int qt = 0; qt < 4; ++qt) {
#pragma unroll
        for (int hh = 0; hh < 2; ++hh)
            qf[qt][hh] = *(const frag8*)(qbase + (size_t)(q0 + qt * 16 + lr) * HD_ + hh * 32 + lg * 8);
    }

    hv4 sel, one1;
#pragma unroll
    for (int j = 0; j < 4; ++j) {
        sel[j]  = (lr == 0) ? (_Float16)1.f : (_Float16)0.f;
        one1[j] = (lr == 1) ? (_Float16)1.f : (_Float16)0.f;
    }
    const facc4 z4 = {0.f, 0.f, 0.f, 0.f};
    facc4 acc[4] = {};

#define STAGE(c) do {                                                          \
        gld_lds16(kfix + (c) * 64 * HD_ + koff,                                \
                  KsB + ((c) % 3) * 8192 + wbase);                             \
    } while (0)

#define CHUNK(c) do {                                                          \
        __builtin_amdgcn_s_setprio(1);                                         \
        _Pragma("unroll")                                                      \
        for (int ct = 0; ct < 4; ++ct) {                                       \
            const frag8 kf0 = *(const frag8*)(KsB + ((c) % 3) * 8192 + ct * 2048 + off_h0); \
            const frag8 kf1 = *(const frag8*)(KsB + ((c) % 3) * 8192 + ct * 2048 + off_h1); \
            const hv4 vv = *(const hv4*)(Vs + (c) * 64 + ct * 16 + lg * 4);    \
            const hv4 av = vv * sel + one1;                                    \
            _Pragma("unroll")                                                  \
            for (int qt = 0; qt < 4; ++qt) {                                   \
                facc4 s_ = __builtin_amdgcn_mfma_f32_16x16x32_bf16(kf0, qf[qt][0], z4, 0, 0, 0); \
                s_ = __builtin_amdgcn_mfma_f32_16x16x32_bf16(kf1, qf[qt][1], s_, 0, 0, 0); \
                const hv2 p01 = __builtin_bit_cast(hv2,                        \
                    __builtin_amdgcn_cvt_pkrtz(__builtin_amdgcn_exp2f(s_[0]),  \
                                               __builtin_amdgcn_exp2f(s_[1]))); \
                const hv2 p23 = __builtin_bit_cast(hv2,                        \
                    __builtin_amdgcn_cvt_pkrtz(__builtin_amdgcn_exp2f(s_[2]),  \
                                               __builtin_amdgcn_exp2f(s_[3]))); \
                hv4 pb; pb[0] = p01[0]; pb[1] = p01[1]; pb[2] = p23[0]; pb[3] = p23[1]; \
                acc[qt] = __builtin_amdgcn_mfma_f32_16x16x16f16(av, pb, acc[qt], 0, 0, 0); \
            }                                                                  \
        }                                                                      \
        __builtin_amdgcn_s_setprio(0);                                         \
    } while (0)

#define ITER_S(c, Nw) {                                                        \
        asm volatile("s_waitcnt vmcnt(" Nw ")" ::: "memory");                  \
        __builtin_amdgcn_s_barrier();                                          \
        asm volatile("" ::: "memory");                                         \
        STAGE((c) + 2);                                                        \
        CHUNK(c);                                                              \
    }
#define ITER_N(c, Nw) {                                                        \
        asm volatile("s_waitcnt vmcnt(" Nw ")" ::: "memory");                  \
        __builtin_amdgcn_s_barrier();                                          \
        asm volatile("" ::: "memory");                                         \
        CHUNK(c);                                                              \
    }

    STAGE(0);
    STAGE(1);
    __syncthreads();   // Vs visible to all waves (full drain once, prologue only)
    ITER_S(0, "1") ITER_S(1, "1") ITER_S(2, "1") ITER_S(3, "1")
    ITER_S(4, "1") ITER_S(5, "1") ITER_N(6, "1") ITER_N(7, "0")

#undef STAGE
#undef CHUNK
#undef ITER_S
#undef ITER_N

    if (lg == 0) {
#pragma unroll
        for (int qt = 0; qt < 4; ++qt) {
            const int row = q0 + qt * 16 + lr;
            float2 pr; pr.x = acc[qt][0]; pr.y = acc[qt][1];
            part[(size_t)split * (M_ * HEAD_) + ((size_t)(b * N_ + row)) * HEAD_ + h] = pr;
        }
    }
}

// ---------------- Kernel 4: combine split-KV partials --------------------
__global__ __launch_bounds__(256) void reduce_kernel(const float2* __restrict__ part,
                                                     const float* __restrict__ Ain,
                                                     float* __restrict__ outp) {
    const int i = blockIdx.x * 256 + threadIdx.x;   // 0..131071 == out layout
    const float2 p0 = part[i];
    const float2 p1 = part[1 * (M_ * HEAD_) + i];
    const float2 p2 = part[2 * (M_ * HEAD_) + i];
    const float2 p3 = part[3 * (M_ * HEAD_) + i];
    outp[i] = Ain[i] + (p0.x + p1.x + p2.x + p3.x) / (p0.y + p1.y + p2.y + p3.y);
}

// ---------------- launch ----------------
extern "C" void kernel_launch(void* const* d_in, const int* in_sizes, int n_in,
                              void* d_out, int out_size, void* d_ws, size_t ws_size,
                              hipStream_t stream) {
    const float* x   = (const float*)d_in[0];
    const float* A   = (const float*)d_in[1];
    const float* lw  = (const float*)d_in[2];
    const float* lb  = (const float*)d_in[3];
    const float* Wqk = (const float*)d_in[4];
    const float* wv  = (const float*)d_in[5];
    float* outp = (float*)d_out;

    char* ws = (char*)d_ws;
    unsigned short* xn  = (unsigned short*)(ws);                      // 16 MB (dead after gemm)
    unsigned short* wb  = (unsigned short*)(ws + 16u * 1024 * 1024);  //  4 MB
    unsigned short* qb  = (unsigned short*)(ws + 20u * 1024 * 1024);  // 16 MB
    unsigned short* kb  = (unsigned short*)(ws + 36u * 1024 * 1024);  // 16 MB
    unsigned short* v16 = (unsigned short*)(ws + 52u * 1024 * 1024);  // 256 KB
    float2*         part = (float2*)(ws);                             // 4 MB, reuses xn region

    prep_kernel<<<M_ + 2048 + B_ * HEAD_, 256, 0, stream>>>(x, lw, lb, Wqk, A, wv, xn, wb, v16);
    gemm_qk<<<256, 512, 0, stream>>>(xn, wb, qb, kb);
    attn_kernel<<<1024, 512, 0, stream>>>(qb, kb, v16, part);
    reduce_kernel<<<(M_ * HEAD_) / 256, 256, 0, stream>>>(part, A, outp);
}